// Round 6
// baseline (1856.702 us; speedup 1.0000x reference)
//
#include <hip/hip_runtime.h>
#include <stdint.h>

typedef __bf16 bf16;
typedef __attribute__((ext_vector_type(8))) __bf16 bf16x8;
typedef __attribute__((ext_vector_type(4))) float floatx4;

__device__ inline float bflo(uint32_t u){ union{uint32_t v; float f;} t; t.v = u << 16; return t.f; }
__device__ inline float bfhi(uint32_t u){ union{uint32_t v; float f;} t; t.v = u & 0xffff0000u; return t.f; }
__device__ inline uint32_t pack2(float a, float b){ union{ bf16 h[2]; uint32_t u; } t; t.h[0]=(bf16)a; t.h[1]=(bf16)b; return t.u; }

__device__ inline void load4(const bf16* p, float* x){
  uint2 u = *(const uint2*)p; x[0]=bflo(u.x); x[1]=bfhi(u.x); x[2]=bflo(u.y); x[3]=bfhi(u.y);
}
__device__ inline void load4(const float* p, float* x){
  float4 u = *(const float4*)p; x[0]=u.x; x[1]=u.y; x[2]=u.z; x[3]=u.w;
}

// async global->LDS, 16B per lane (dest must be wave-uniform base + lane*16)
__device__ inline void gload16(const void* g, void* l){
  __builtin_amdgcn_global_load_lds((const __attribute__((address_space(1))) uint32_t*)g,
                                   (__attribute__((address_space(3))) uint32_t*)l, 16, 0, 0);
}

// ---------------- f32 -> bf16 weight conversion ----------------
__global__ __launch_bounds__(256) void cvt_kernel(const float* __restrict__ in, bf16* __restrict__ out,
                                                  int n8, float scale)
{
  int i = blockIdx.x * 256 + threadIdx.x;
  if (i >= n8) return;
  const float* p = in + (size_t)i * 8;
  float4 a = *(const float4*)p;
  float4 b = *(const float4*)(p + 4);
  union{ uint4 q; bf16 h[8]; } pk;
  pk.h[0]=(bf16)(a.x*scale); pk.h[1]=(bf16)(a.y*scale); pk.h[2]=(bf16)(a.z*scale); pk.h[3]=(bf16)(a.w*scale);
  pk.h[4]=(bf16)(b.x*scale); pk.h[5]=(bf16)(b.y*scale); pk.h[6]=(bf16)(b.z*scale); pk.h[7]=(bf16)(b.w*scale);
  *(uint4*)(out + (size_t)i*8) = pk.q;
}

// ---------------- fused QKV bias vector: [q_b*0.125 | 0 | v_b] ----------------
__global__ __launch_bounds__(256) void qkvb_fill(const float* __restrict__ qb, const float* __restrict__ vb,
                                                 float* __restrict__ out)
{
  int i = blockIdx.x * 256 + threadIdx.x;   // 3072
  float v = 0.f;
  if (i < 1024) v = qb[i] * 0.125f;
  else if (i >= 2048) v = vb[i - 2048];
  out[i] = v;
}

// ---------------- rel-pos bias matrix precompute: biasB[h][272][272] bf16; kg>256 = -3e38 (mask) ----------------
__global__ __launch_bounds__(256) void bias_fill(const float* __restrict__ tab, bf16* __restrict__ biasB)
{
  int t = blockIdx.x * 256 + threadIdx.x;
  if (t >= 16*272*272) return;
  int kg = t % 272;
  int rem = t / 272;
  int qg = rem % 272;
  int h = rem / 272;
  float v;
  if (kg > 256) v = -3e38f;
  else {
    int qq = min(qg, 256);
    int idx;
    if (qq == 0 && kg == 0) idx = 963;
    else if (qq == 0) idx = 961;
    else if (kg == 0) idx = 962;
    else { int p = qq - 1, pk = kg - 1;
           idx = ((p >> 4) - (pk >> 4) + 15) * 31 + ((p & 15) - (pk & 15) + 15); }
    v = tab[idx*16 + h];
  }
  biasB[t] = (bf16)v;
}

// ---------------- LayerNorm (row-per-block, width W). In-place safe. ----------------
template<int W, typename TIN>
__global__ __launch_bounds__(256) void ln_kernel(const TIN* in, const float* __restrict__ g,
                                                 const float* __restrict__ bb, bf16* out, int M)
{
  constexpr int E = W / 256;
  int row = blockIdx.x; if (row >= M) return;
  int tid = threadIdx.x;
  const TIN* rp = in + (size_t)row * W + tid * E;
  float x[E];
  #pragma unroll
  for (int j = 0; j < E; j += 4) load4(rp + j, &x[j]);
  float s = 0.f, ss = 0.f;
  #pragma unroll
  for (int e = 0; e < E; e++){ s += x[e]; ss += x[e]*x[e]; }
  #pragma unroll
  for (int k = 32; k >= 1; k >>= 1){ s += __shfl_xor(s, k, 64); ss += __shfl_xor(ss, k, 64); }
  __shared__ float rs_[4], rq_[4];
  if ((tid & 63) == 0){ rs_[tid >> 6] = s; rq_[tid >> 6] = ss; }
  __syncthreads();
  s = rs_[0]+rs_[1]+rs_[2]+rs_[3]; ss = rq_[0]+rq_[1]+rq_[2]+rq_[3];
  float mean = s * (1.0f / W);
  float var  = ss * (1.0f / W) - mean * mean;
  float rinv = rsqrtf(var + 1e-5f);
  bf16* op = out + (size_t)row * W + tid * E;
  const float* gp = g + tid * E;
  const float* bp = bb + tid * E;
  #pragma unroll
  for (int j = 0; j < E; j += 4){
    float gv[4], bv[4];
    load4(gp + j, gv); load4(bp + j, bv);
    float y0 = (x[j]  -mean)*rinv*gv[0] + bv[0];
    float y1 = (x[j+1]-mean)*rinv*gv[1] + bv[1];
    float y2 = (x[j+2]-mean)*rinv*gv[2] + bv[2];
    float y3 = (x[j+3]-mean)*rinv*gv[3] + bv[3];
    uint2 o; o.x = pack2(y0, y1); o.y = pack2(y2, y3);
    *(uint2*)(op + j) = o;
  }
}

// ---------------- NT GEMM 128x128 (proven; used for N=1024 shapes: proj, w3) ----------------
template<typename TE, typename TC>
__global__ __launch_bounds__(256) void gemm_bt(const bf16* __restrict__ A, const bf16* __restrict__ Bw,
                                               const float* __restrict__ bias, const TE* extra,
                                               TC* C, int M, int N, int K, int mode)
{
  __shared__ __align__(16) bf16 As[128*32];
  __shared__ __align__(16) bf16 Bs[128*32];
  int tid = threadIdx.x;
  int lane = tid & 63, wave = tid >> 6;
  int l16 = lane & 15, quad = lane >> 4;
  int wm = wave >> 1, wn = wave & 1;
  int m0 = blockIdx.y * 128, n0 = blockIdx.x * 128;
  floatx4 acc[4][4];
  #pragma unroll
  for (int i = 0; i < 4; i++)
    #pragma unroll
    for (int j = 0; j < 4; j++) acc[i][j] = (floatx4){0.f,0.f,0.f,0.f};
  int nk = K >> 5;
  int rowS = tid >> 2;
  int colS = (tid & 3) * 8;
  int ra0 = min(m0 + rowS,      M-1);
  int ra1 = min(m0 + 64 + rowS, M-1);
  int rb0 = min(n0 + rowS,      N-1);
  int rb1 = min(n0 + 64 + rowS, N-1);
  const bf16* pa0 = A  + (size_t)ra0 * K + colS;
  const bf16* pa1 = A  + (size_t)ra1 * K + colS;
  const bf16* pb0 = Bw + (size_t)rb0 * K + colS;
  const bf16* pb1 = Bw + (size_t)rb1 * K + colS;
  bf16* la0 = &As[tid*8];        bf16* la1 = &As[2048 + tid*8];
  bf16* lb0 = &Bs[tid*8];        bf16* lb1 = &Bs[2048 + tid*8];
  auto stage = [&](int kt){
    int ko = kt * 32;
    gload16(pa0 + ko, la0);
    gload16(pa1 + ko, la1);
    gload16(pb0 + ko, lb0);
    gload16(pb1 + ko, lb1);
  };
  stage(0);
  int kt = 0;
  while (true){
    __syncthreads();
    bf16x8 af[4], bfv[4];
    #pragma unroll
    for (int i = 0; i < 4; i++) af[i]  = *(const bf16x8*)&As[(wm*64 + i*16 + l16)*32 + quad*8];
    #pragma unroll
    for (int j = 0; j < 4; j++) bfv[j] = *(const bf16x8*)&Bs[(wn*64 + j*16 + l16)*32 + quad*8];
    ++kt;
    bool more = kt < nk;
    if (more){
      __syncthreads();
      stage(kt);
    }
    #pragma unroll
    for (int i = 0; i < 4; i++)
      #pragma unroll
      for (int j = 0; j < 4; j++)
        acc[i][j] = __builtin_amdgcn_mfma_f32_16x16x32_bf16(af[i], bfv[j], acc[i][j], 0, 0, 0);
    if (!more) break;
  }
  #pragma unroll
  for (int i = 0; i < 4; i++){
    int gmb = m0 + wm*64 + i*16 + quad*4;
    #pragma unroll
    for (int j = 0; j < 4; j++){
      int gn = n0 + wn*64 + j*16 + l16;
      float bv = bias ? bias[gn] : 0.f;
      #pragma unroll
      for (int r = 0; r < 4; r++){
        int gm = gmb + r;
        if (gm < M){
          float v = acc[i][j][r] + bv;
          if (mode == 1) v += (float)extra[(size_t)gm * N + gn];
          else if (mode == 2){ float a = (float)extra[(size_t)gm * N + gn]; v *= a / (1.f + __expf(-a)); }
          C[(size_t)gm * N + gn] = (TC)v;
        }
      }
    }
  }
}

// ---------------- NT GEMM 256x256, BK=64, 8 waves, dbuf LDS + counted vmcnt + T2 swizzle ----------------
// Deep-pipeline structure (T3/T4): stage(k+1) issued BEFORE compute(k); s_waitcnt vmcnt(8) (not 0) keeps
// next tile's 8 loads in flight across the barrier. LDS XOR-swizzle (T2) via pre-swizzled global source
// (global_load_lds writes linearly) + matching XOR on ds_read_b128 -> 2 lanes/bank (free).
template<typename TE, typename TC>
__global__ __launch_bounds__(512) void gemm256(const bf16* __restrict__ A, const bf16* __restrict__ Bw,
                                               const float* __restrict__ bias, const TE* extra,
                                               TC* C, int M, int N, int K, int mode)
{
  __shared__ __align__(16) bf16 lds[65536];       // 128 KiB: A dbuf 2x32KB, B dbuf 2x32KB
  int tid = threadIdx.x;
  int lane = tid & 63, wave = tid >> 6;
  int l16 = lane & 15, quad = lane >> 4;
  int wm = wave >> 2, wn = wave & 3;              // 2 x 4 wave grid; per-wave output 128 x 64

  // bijective XCD swizzle (m204): contiguous grid chunk per XCD for L2 panel reuse
  int nwg = gridDim.x * gridDim.y;
  int orig = blockIdx.y * gridDim.x + blockIdx.x;
  int qq = nwg >> 3, rr = nwg & 7;
  int xcd = orig & 7, idx = orig >> 3;
  int wg = (xcd < rr ? xcd*(qq+1) : rr*(qq+1) + (xcd-rr)*qq) + idx;
  int bx = wg % gridDim.x, by = wg / gridDim.x;
  int m0 = by * 256, n0 = bx * 256;

  floatx4 acc[8][4];
  #pragma unroll
  for (int i = 0; i < 8; i++)
    #pragma unroll
    for (int j = 0; j < 4; j++) acc[i][j] = (floatx4){0.f,0.f,0.f,0.f};
  int nk = K >> 6;

  // staging: per K-tile, A half = 256x64 bf16 = 32KB = 4 issues x (512 thr x 16B); B same -> 8 gload16/thread
  int srow = tid >> 3, sseg = tid & 7;            // 64 rows x 8 segs per issue
  int sA = ((sseg ^ (srow & 7)) << 3);            // pre-swizzled SOURCE column (elements)
  const bf16* pA[4]; const bf16* pB[4];
  #pragma unroll
  for (int jj = 0; jj < 4; jj++){
    pA[jj] = A  + (size_t)min(m0 + jj*64 + srow, M-1) * K + sA;
    pB[jj] = Bw + (size_t)min(n0 + jj*64 + srow, N-1) * K + sA;
  }
  auto stage = [&](int kt, int b){
    int ko = kt * 64;
    bf16* as = lds + (b ? 16384 : 0);
    bf16* bs = lds + 32768 + (b ? 16384 : 0);
    #pragma unroll
    for (int jj = 0; jj < 4; jj++){
      gload16(pA[jj] + ko, as + jj*4096 + tid*8);
      gload16(pB[jj] + ko, bs + jj*4096 + tid*8);
    }
  };

  stage(0, 0);
  int cur = 0;
  for (int kt = 0; kt < nk; ++kt){
    bool more = (kt + 1) < nk;
    if (more){
      stage(kt + 1, cur ^ 1);                                 // 8 loads fly under compute
      asm volatile("s_waitcnt vmcnt(8)" ::: "memory");        // current tile's 8 loads retired
    } else {
      asm volatile("s_waitcnt vmcnt(0)" ::: "memory");
    }
    __builtin_amdgcn_s_barrier();
    asm volatile("" ::: "memory");
    bf16* as = lds + (cur ? 16384 : 0);
    bf16* bs = lds + 32768 + (cur ? 16384 : 0);
    #pragma unroll
    for (int kk = 0; kk < 2; kk++){
      bf16x8 af[8], bfv[4];
      #pragma unroll
      for (int i = 0; i < 8; i++){
        int r = wm*128 + i*16 + l16;
        af[i] = *(const bf16x8*)&as[r*64 + (((kk*4 + quad) ^ (l16 & 7)) << 3)];
      }
      #pragma unroll
      for (int j = 0; j < 4; j++){
        int c = wn*64 + j*16 + l16;
        bfv[j] = *(const bf16x8*)&bs[c*64 + (((kk*4 + quad) ^ (l16 & 7)) << 3)];
      }
      __builtin_amdgcn_s_setprio(1);
      #pragma unroll
      for (int i = 0; i < 8; i++)
        #pragma unroll
        for (int j = 0; j < 4; j++)
          acc[i][j] = __builtin_amdgcn_mfma_f32_16x16x32_bf16(af[i], bfv[j], acc[i][j], 0, 0, 0);
      __builtin_amdgcn_s_setprio(0);
    }
    asm volatile("" ::: "memory");
    __builtin_amdgcn_s_barrier();                             // all reads of cur done before it's restaged
    cur ^= 1;
  }

  #pragma unroll
  for (int i = 0; i < 8; i++){
    int gmb = m0 + wm*128 + i*16 + quad*4;
    #pragma unroll
    for (int j = 0; j < 4; j++){
      int gn = n0 + wn*64 + j*16 + l16;
      float bv = bias ? bias[gn] : 0.f;
      #pragma unroll
      for (int r = 0; r < 4; r++){
        int gm = gmb + r;
        if (gm < M){
          float v = acc[i][j][r] + bv;
          if (mode == 1) v += (float)extra[(size_t)gm * N + gn];
          else if (mode == 2){ float a = (float)extra[(size_t)gm * N + gn]; v *= a / (1.f + __expf(-a)); }
          C[(size_t)gm * N + gn] = (TC)v;
        }
      }
    }
  }
}

// ---------------- RoPE on fused QKV buffer [M][3072]: q at +0, k at +1024; tokens 1..256 ----------------
__global__ __launch_bounds__(256) void rope_kernel(bf16* __restrict__ qkv,
                                                   const float* __restrict__ cs, const float* __restrict__ sn)
{
  uint32_t i = blockIdx.x * 256u + threadIdx.x;   // 64*256*512 pairs
  int d0 = (int)(i & 511) * 2;
  int tok = (int)((i >> 9) & 255);
  int b = (int)(i >> 17);
  int j = d0 & 63;
  float c0 = cs[tok*64 + j], c1 = cs[tok*64 + j + 1];
  float s0 = sn[tok*64 + j], s1 = sn[tok*64 + j + 1];
  size_t off = ((size_t)(b*257 + tok + 1)) * 3072 + d0;
  uint32_t uq = *(const uint32_t*)(qkv + off);
  float x0 = bflo(uq), x1 = bfhi(uq);
  *(uint32_t*)(qkv + off) = pack2(x0*c0 - x1*s0, x1*c1 + x0*s1);
  uint32_t uk = *(const uint32_t*)(qkv + off + 1024);
  float y0 = bflo(uk), y1 = bfhi(uk);
  *(uint32_t*)(qkv + off + 1024) = pack2(y0*c0 - y1*s0, y1*c1 + y0*s1);
}

// ---------------- attention (unchanged from passing round 5) ----------------
__global__ __launch_bounds__(256, 2) void attn_kernel(const bf16* __restrict__ QKV,
                                                      const bf16* __restrict__ biasB,
                                                      bf16* __restrict__ AO)
{
  constexpr int VS = 280;
  __shared__ __align__(16) bf16 Ks[272*64];
  __shared__ __align__(16) bf16 Vt[64*VS];
  __shared__ __align__(16) bf16 Os[4][16*72];
  int id = blockIdx.x;
  int h = id & 15, b = id >> 4;
  int tid = threadIdx.x, lane = tid & 63, wave = tid >> 6;
  int l16 = lane & 15, quad = lane >> 4;
  size_t baseQ = (size_t)(b*257) * 3072 + h*64;
  const bf16* Kg = QKV + baseQ + 1024;
  const bf16* Vg = QKV + baseQ + 2048;
  size_t aoBase = (size_t)(b*257) * 1024 + h*64;

  for (int i = tid; i < 272*8; i += 256){
    int row = i >> 3, seg = i & 7;
    int tok = min(row, 256);
    gload16(Kg + (size_t)tok*3072 + ((seg ^ (row & 7)) * 8), &Ks[i*8]);
  }
  for (int i = tid; i < 272*8; i += 256){
    int row = i >> 3, seg = i & 7;
    int tok = min(row, 256);
    uint4 v = *(const uint4*)(Vg + (size_t)tok*3072 + seg*8);
    uint4 w;
    w.x = (uint32_t)__shfl_xor((int)v.x, 8, 64);
    w.y = (uint32_t)__shfl_xor((int)v.y, 8, 64);
    w.z = (uint32_t)__shfl_xor((int)v.z, 8, 64);
    w.w = (uint32_t)__shfl_xor((int)v.w, 8, 64);
    union { uint4 q4; bf16 h8[8]; } mv, pv; mv.q4 = v; pv.q4 = w;
    int rb = row & ~1;
    if ((row & 1) == 0){
      #pragma unroll
      for (int jj = 0; jj < 4; jj++){
        union { uint32_t u; bf16 hh[2]; } pk; pk.hh[0] = mv.h8[jj]; pk.hh[1] = pv.h8[jj];
        *(uint32_t*)&Vt[(seg*8 + jj)*VS + rb] = pk.u;
      }
    } else {
      #pragma unroll
      for (int jj = 4; jj < 8; jj++){
        union { uint32_t u; bf16 hh[2]; } pk; pk.hh[0] = pv.h8[jj]; pk.hh[1] = mv.h8[jj];
        *(uint32_t*)&Vt[(seg*8 + jj)*VS + rb] = pk.u;
      }
    }
  }
  __syncthreads();

  int srcA = l16 + 16*((2*quad)     & 3);
  int srcB = l16 + 16*((2*quad + 1) & 3);

  for (int qt = wave; qt < 17; qt += 4){
    int q0 = qt * 16;
    int qrow = min(q0 + l16, 256);
    const bf16* qp = QKV + baseQ + (size_t)qrow*3072;
    bf16x8 qb0 = *(const bf16x8*)(qp + quad*8);
    bf16x8 qb1 = *(const bf16x8*)(qp + 32 + quad*8);

    const bf16* bp = biasB + ((size_t)(h*272) + (q0 + l16)) * 272;
    uint2 bu[17];
    #pragma unroll
    for (int nt = 0; nt < 17; nt++) bu[nt] = *(const uint2*)(bp + nt*16 + quad*4);

    floatx4 S[17];
    #pragma unroll
    for (int nt = 0; nt < 17; nt++){
      int row = nt*16 + l16;
      bf16x8 ka0 = *(const bf16x8*)&Ks[row*64 + ((quad     ^ (l16 & 7)) * 8)];
      bf16x8 ka1 = *(const bf16x8*)&Ks[row*64 + (((4+quad) ^ (l16 & 7)) * 8)];
      floatx4 c = (floatx4){0.f,0.f,0.f,0.f};
      c = __builtin_amdgcn_mfma_f32_16x16x32_bf16(ka0, qb0, c, 0, 0, 0);
      c = __builtin_amdgcn_mfma_f32_16x16x32_bf16(ka1, qb1, c, 0, 0, 0);
      S[nt] = c;
    }

    float m = -3e38f;
    #pragma unroll
    for (int nt = 0; nt < 17; nt++){
      S[nt][0] += bflo(bu[nt].x); S[nt][1] += bfhi(bu[nt].x);
      S[nt][2] += bflo(bu[nt].y); S[nt][3] += bfhi(bu[nt].y);
      m = fmaxf(m, fmaxf(fmaxf(S[nt][0], S[nt][1]), fmaxf(S[nt][2], S[nt][3])));
    }
    m = fmaxf(m, __shfl_xor(m, 16, 64));
    m = fmaxf(m, __shfl_xor(m, 32, 64));

    float lsum = 0.f;
    uint32_t pklo[17], pkhi[17];
    #pragma unroll
    for (int nt = 0; nt < 17; nt++){
      float p0 = __expf(S[nt][0] - m), p1 = __expf(S[nt][1] - m);
      float p2 = __expf(S[nt][2] - m), p3 = __expf(S[nt][3] - m);
      lsum += (p0 + p1) + (p2 + p3);
      pklo[nt] = pack2(p0, p1); pkhi[nt] = pack2(p2, p3);
    }
    lsum += __shfl_xor(lsum, 16, 64);
    lsum += __shfl_xor(lsum, 32, 64);

    floatx4 o[4];
    #pragma unroll
    for (int dt = 0; dt < 4; dt++) o[dt] = (floatx4){0.f,0.f,0.f,0.f};
    #pragma unroll
    for (int ks = 0; ks < 9; ks++){
      uint32_t t0[4], t1[4];
      t0[0] = (uint32_t)__shfl((int)pklo[2*ks], srcA, 64);
      t0[1] = (uint32_t)__shfl((int)pkhi[2*ks], srcA, 64);
      t0[2] = (uint32_t)__shfl((int)pklo[2*ks], srcB, 64);
      t0[3] = (uint32_t)__shfl((int)pkhi[2*ks], srcB, 64);
      if (2*ks + 1 <= 16){
        t1[0] = (uint32_t)__shfl((int)pklo[2*ks+1], srcA, 64);
        t1[1] = (uint32_t)__shfl((int)pkhi[2*ks+1], srcA, 64);
        t1[2] = (uint32_t)__shfl((int)pklo[2*ks+1], srcB, 64);
        t1[3] = (uint32_t)__shfl((int)pkhi[2*ks+1], srcB, 64);
      } else {
        t1[0] = 0; t1[1] = 0; t1[2] = 0; t1[3] = 0;
      }
      union { uint32_t u[4]; bf16x8 v; } pa;
      bool lowhalf = (quad < 2);
      pa.u[0] = lowhalf ? t0[0] : t1[0];
      pa.u[1] = lowhalf ? t0[1] : t1[1];
      pa.u[2] = lowhalf ? t0[2] : t1[2];
      pa.u[3] = lowhalf ? t0[3] : t1[3];
      #pragma unroll
      for (int dt = 0; dt < 4; dt++){
        bf16x8 vb = *(const bf16x8*)&Vt[(dt*16 + l16)*VS + ks*32 + quad*8];
        o[dt] = __builtin_amdgcn_mfma_f32_16x16x32_bf16(pa.v, vb, o[dt], 0, 0, 0);
      }
    }

    #pragma unroll
    for (int r = 0; r < 4; r++){
      int qr = quad*4 + r;
      float ls = __shfl(lsum, qr, 64);
      float rinv = 1.0f / ls;
      #pragma unroll
      for (int dt = 0; dt < 4; dt++)
        Os[wave][qr*72 + dt*16 + l16] = (bf16)(o[dt][r] * rinv);
    }
    #pragma unroll
    for (int half = 0; half < 2; half++){
      int rowL = (lane >> 3) + half*8;
      int chunk = lane & 7;
      int q = q0 + rowL;
      uint4 ov = *(const uint4*)&Os[wave][rowL*72 + chunk*8];
      if (q <= 256) *(uint4*)&AO[aoBase + (size_t)q*1024 + chunk*8] = ov;
    }
  }
}

extern "C" void kernel_launch(void* const* d_in, const int* in_sizes, int n_in,
                              void* d_out, int out_size, void* d_ws, size_t ws_size,
                              hipStream_t stream)
{
  (void)in_sizes; (void)n_in; (void)out_size; (void)ws_size;
  const float* x    = (const float*)d_in[0];
  const float* rc   = (const float*)d_in[1];
  const float* rsn  = (const float*)d_in[2];
  const float* q_w  = (const float*)d_in[3];
  const float* q_b  = (const float*)d_in[4];
  const float* k_w  = (const float*)d_in[5];
  const float* v_w  = (const float*)d_in[6];
  const float* v_b  = (const float*)d_in[7];
  const float* tab  = (const float*)d_in[8];
  const float* ig   = (const float*)d_in[9];
  const float* ib   = (const float*)d_in[10];
  const float* pw   = (const float*)d_in[11];
  const float* pb   = (const float*)d_in[12];
  const float* n1g  = (const float*)d_in[13];
  const float* n1b  = (const float*)d_in[14];
  const float* n2g  = (const float*)d_in[15];
  const float* n2b  = (const float*)d_in[16];
  const float* w1w  = (const float*)d_in[17];
  const float* w1b  = (const float*)d_in[18];
  const float* w2w  = (const float*)d_in[19];
  const float* w2b  = (const float*)d_in[20];
  const float* fg   = (const float*)d_in[21];
  const float* fb   = (const float*)d_in[22];
  const float* w3w  = (const float*)d_in[23];
  const float* w3b  = (const float*)d_in[24];

  const int M = 64 * 257;        // 16448
  const int D = 1024, HD = 4096;
  char* ws = (char*)d_ws;
  const size_t CHB = (size_t)M * D * 2;          // 33,685,504 B
  bf16* B0 = (bf16*)(ws);
  bf16* B1 = (bf16*)(ws + CHB);
  bf16* B2 = (bf16*)(ws + 2*CHB);
  bf16* B3 = (bf16*)(ws + 3*CHB);
  bf16* WQ = (bf16*)(ws + 4*CHB);
  bf16* WK = WQ + (size_t)D*D;
  bf16* WV = WK + (size_t)D*D;
  bf16* WP = WV + (size_t)D*D;
  bf16* W1 = WP + (size_t)D*D;
  bf16* W2 = W1 + (size_t)HD*D;
  bf16* W3 = W2 + (size_t)HD*D;
  float* QKVB = (float*)(W3 + (size_t)HD*D);
  bf16* XN  = B0;          // LN1 out
  bf16* QKV = B1;          // fused [M][3072] spans B1..B3
  bf16* AO  = B0;          // XN dead after QKV GEMM
  bf16* AOL = B1;          // QKV dead after attention
  bf16* X1  = B2;
  bf16* XN2 = B3;
  bf16* HS  = B0;          // spans B0+B1 during FFN
  bf16* biasB = (bf16*)d_out;   // 2.37 MB scratch in d_out; dead before FFN writes OUT
  float* OUT = (float*)d_out;

  dim3 blk(256), blk2(512);
  dim3 g1(D/128, (M + 127)/128);
  dim3 gqkv(3072/256, (M + 255)/256);

  const int n8_D = D*D/8;
  const int n8_H = HD*D/8;
  cvt_kernel<<<dim3(n8_D/256), blk, 0, stream>>>(q_w, WQ, n8_D, 0.125f);
  cvt_kernel<<<dim3(n8_D/256), blk, 0, stream>>>(k_w, WK, n8_D, 1.f);
  cvt_kernel<<<dim3(n8_D/256), blk, 0, stream>>>(v_w, WV, n8_D, 1.f);
  cvt_kernel<<<dim3(n8_D/256), blk, 0, stream>>>(pw,  WP, n8_D, 1.f);
  cvt_kernel<<<dim3(n8_H/256), blk, 0, stream>>>(w1w, W1, n8_H, 1.f);
  cvt_kernel<<<dim3(n8_H/256), blk, 0, stream>>>(w2w, W2, n8_H, 1.f);
  cvt_kernel<<<dim3(n8_H/256), blk, 0, stream>>>(w3w, W3, n8_H, 1.f);
  qkvb_fill<<<dim3(12), blk, 0, stream>>>(q_b, v_b, QKVB);
  bias_fill<<<dim3((16*272*272 + 255)/256), blk, 0, stream>>>(tab, biasB);

  ln_kernel<1024, float><<<dim3(M), blk, 0, stream>>>(x, n1g, n1b, XN, M);
  gemm256<bf16, bf16><<<gqkv, blk2, 0, stream>>>(XN, WQ, QKVB, (const bf16*)nullptr, QKV, M, 3072, D, 0);
  rope_kernel<<<dim3(64*256*512/256), blk, 0, stream>>>(QKV, rc, rsn);
  attn_kernel<<<dim3(64*16), blk, 0, stream>>>(QKV, biasB, AO);
  ln_kernel<1024, bf16><<<dim3(M), blk, 0, stream>>>(AO, ig, ib, AOL, M);
  gemm_bt<float, bf16><<<g1, blk, 0, stream>>>(AOL, WP, pb, x, X1, M, D, D, 1);
  ln_kernel<1024, bf16><<<dim3(M), blk, 0, stream>>>(X1, n2g, n2b, XN2, M);

  const int MC = M / 2;                       // 8224
  dim3 g2(HD/256, (MC + 255)/256);
  dim3 g1c(D/128, (MC + 127)/128);
  for (int c = 0; c < 2; c++){
    const bf16* a2 = XN2 + (size_t)c * MC * D;
    const bf16* x1 = X1  + (size_t)c * MC * D;
    float*      oc = OUT + (size_t)c * MC * D;
    gemm256<bf16, bf16><<<g2, blk2, 0, stream>>>(a2, W1, w1b, (const bf16*)nullptr, HS, MC, HD, D, 0);
    gemm256<bf16, bf16><<<g2, blk2, 0, stream>>>(a2, W2, w2b, HS, HS, MC, HD, D, 2);
    ln_kernel<4096, bf16><<<dim3(MC), blk, 0, stream>>>(HS, fg, fb, HS, MC);
    gemm_bt<bf16, float><<<g1c, blk, 0, stream>>>(HS, W3, w3b, x1, oc, MC, D, HD, 1);
  }
}